// Round 6
// baseline (232.618 us; speedup 1.0000x reference)
//
#include <hip/hip_runtime.h>
#include <math.h>

#define BB 2
#define LSEQ 2048
#define H 32
#define PDIM 64
#define NDIM 128
#define CS 256
#define NC 8

typedef _Float16 half8 __attribute__((ext_vector_type(8)));
typedef float floatx4 __attribute__((ext_vector_type(4)));

// ---------------- ws layout (bytes) ----------------
// cum      : f32 [bz=16][H][CS]               @ 0         (512 KB)
// cA       : f32 [bz][H][CS]  (dtf*xs)        @ 524288    (512 KB)
// CBh      : f16 [bz][l16=16][s8=32][16][8]   @ 1048576   (2 MB)  MFMA-tiled, causal only
// statesHT : f16 [bzh][p16=4][n8=16][16][8]   @ 3145728   (8 MB)  prev-state/16
// Bt16T    : f16 [bz][n16=8][s8=32][16][8]    @ 11534336  (1 MB)
// C16T     : f16 [bz][l16=16][n8=16][16][8]   @ 12582912  (1 MB)
// x8       : i8  [b][l][h][p]                 @ 13631488  (8 MB)

__device__ __forceinline__ int dot4i8(int a, int b, int c) {
#if __has_builtin(__builtin_amdgcn_sdot4)
    return __builtin_amdgcn_sdot4(a, b, c, false);
#else
    c += ((a << 24) >> 24) * ((b << 24) >> 24);
    c += ((a << 16) >> 24) * ((b << 16) >> 24);
    c += ((a << 8) >> 24) * ((b << 8) >> 24);
    c += (a >> 24) * (b >> 24);
    return c;
#endif
}

// kA: CBh Gram (causal 64x64 tiles, f16) + Bt16T/C16T prep
__global__ __launch_bounds__(256) void kA(
    const int* __restrict__ Bm, const int* __restrict__ Cm,
    const float* __restrict__ Bs_p, const float* __restrict__ Cs_p,
    _Float16* __restrict__ CBh, _Float16* __restrict__ Bt16T, _Float16* __restrict__ C16T)
{
    __shared__ int Bi[64][33];
    __shared__ int Ci[64][33];
    int t = threadIdx.x;
    int r = blockIdx.x % 26;
    int zz = blockIdx.x / 26;
    int z = zz & 7, b = zz >> 3;
    int bz = b * NC + z;
    if (r < 10) {
        const int LT[10] = {0,1,1,2,2,2,3,3,3,3};
        const int ST[10] = {0,0,1,0,1,2,0,1,2,3};
        int l0 = LT[r] * 64, s0 = ST[r] * 64;
        const int* Bp = Bm + (size_t)(b * LSEQ + z * CS + s0) * NDIM;
        const int* Cp = Cm + (size_t)(b * LSEQ + z * CS + l0) * NDIM;
        for (int i = t; i < 64 * 32; i += 256) {
            int rr = i >> 5, k = i & 31;
            const int* sb = Bp + rr * NDIM + k * 4;
            const int* sc = Cp + rr * NDIM + k * 4;
            Bi[rr][k] = (sb[0] & 255) | ((sb[1] & 255) << 8) | ((sb[2] & 255) << 16) | ((sb[3] & 255) << 24);
            Ci[rr][k] = (sc[0] & 255) | ((sc[1] & 255) << 8) | ((sc[2] & 255) << 16) | ((sc[3] & 255) << 24);
        }
        __syncthreads();
        float cbscale = (*Bs_p) * (*Cs_p);
        int ll = t & 63, lg = t >> 6;
        int acc[16];
#pragma unroll
        for (int i = 0; i < 16; ++i) acc[i] = 0;
        for (int k = 0; k < 32; ++k) {
            int cw = Ci[ll][k];
#pragma unroll
            for (int si = 0; si < 16; ++si)
                acc[si] = dot4i8(cw, Bi[lg * 16 + si][k], acc[si]);
        }
        int l = l0 + ll;
        int l16 = l >> 4, lm = l & 15;
        int sb8 = (s0 + lg * 16) >> 3;
        _Float16* bp = CBh + ((size_t)(bz * 16 + l16) * 32 + sb8) * 128 + lm * 8;
#pragma unroll
        for (int g = 0; g < 2; ++g) {
            half8 v;
#pragma unroll
            for (int i = 0; i < 8; ++i) v[i] = (_Float16)((float)acc[g * 8 + i] * cbscale);
            *(half8*)(bp + g * 128) = v;
        }
    } else {
        int slice = r - 10;   // 0..15
        {   // C16T: l16 = slice
            int lm = t >> 4, n8 = t & 15;
            const int* cp = Cm + (size_t)(b * LSEQ + z * CS + slice * 16 + lm) * NDIM + n8 * 8;
            int4 c0 = *(const int4*)cp;
            int4 c1 = *(const int4*)(cp + 4);
            half8 v;
            v[0] = (_Float16)(float)c0.x; v[1] = (_Float16)(float)c0.y;
            v[2] = (_Float16)(float)c0.z; v[3] = (_Float16)(float)c0.w;
            v[4] = (_Float16)(float)c1.x; v[5] = (_Float16)(float)c1.y;
            v[6] = (_Float16)(float)c1.z; v[7] = (_Float16)(float)c1.w;
            *(half8*)(C16T + ((size_t)(bz * 16 + slice) * 16 + n8) * 128 + lm * 8) = v;
        }
        {   // Bt16T transpose: n16 = slice&7, s-half = slice>>3
            int nm = t & 15, s8l = t >> 4;
            int n16 = slice & 7, s8 = (slice >> 3) * 16 + s8l;
            const int* bp = Bm + (size_t)(b * LSEQ + z * CS + s8 * 8) * NDIM + n16 * 16 + nm;
            half8 v;
#pragma unroll
            for (int j = 0; j < 8; ++j) v[j] = (_Float16)(float)bp[(size_t)j * NDIM];
            *(half8*)(Bt16T + ((size_t)(bz * 8 + n16) * 32 + s8) * 128 + nm * 8) = v;
        }
    }
}

// kB: fused softplus/cumsum + x transpose/quant + states MFMA + inter-chunk scan.
// grid 512: idx = nh*256 + pq*64 + b*32 + h  (siblings share XCD: strides 64/256 ≡ 0 mod 8)
// block owns p-quarter (16 p) x n-half (64 n); z-loop with register carry.
#define XCB_PITCH 264   // halfs; 528B row -> 16B-aligned, rotating banks
__global__ __launch_bounds__(256) void kB(
    const int* __restrict__ dt, const int* __restrict__ qA, const float* __restrict__ dt_bias,
    const float* __restrict__ A_scale_p, const float* __restrict__ dt_scale_p,
    const int* __restrict__ xq, const float* __restrict__ xs_p, const float* __restrict__ Bs_p,
    const _Float16* __restrict__ Bt16T,
    float* __restrict__ cum, float* __restrict__ cA,
    signed char* __restrict__ x8, _Float16* __restrict__ statesHT)
{
    __shared__ _Float16 xcS[16 * XCB_PITCH];
    __shared__ float wsum[4];
    __shared__ float cumS8[8];
    int t = threadIdx.x;
    int h = blockIdx.x & 31, b = (blockIdx.x >> 5) & 1;
    int pq = (blockIdx.x >> 6) & 3, nh = blockIdx.x >> 8;
    int lane6 = t & 63, w = t >> 6;
    int m = lane6 & 15, q = lane6 >> 4;
    int ntg = nh * 4 + w;                      // this wave's 16-n tile (0..7)
    float A = -__expf((float)qA[h] * (*A_scale_p));
    float dts = *dt_scale_p, bias = dt_bias[h];
    float xs = *xs_p, Bs = *Bs_p;
    bool wr_meta = (pq == 0 && nh == 0);
    bool wr_x8 = (nh == 0);
    float carry[4] = {0.f, 0.f, 0.f, 0.f};

    // prefetch z=0
    float rawv = (float)dt[(size_t)(b * LSEQ + t) * H + h];
    const int* xp0 = xq + ((size_t)(b * LSEQ + t) * H + h) * PDIM + pq * 16;
    int4 xw0 = *(const int4*)xp0, xw1 = *(const int4*)(xp0 + 4);
    int4 xw2 = *(const int4*)(xp0 + 8), xw3 = *(const int4*)(xp0 + 12);

    for (int z = 0; z < NC; ++z) {
        int bz = b * NC + z, bzh = bz * H + h;
        __syncthreads();                       // protect xcS/wsum/cumS8 from prev-iter readers
        // --- softplus + wave scan ---
        float xin = rawv * dts + bias;
        float sp = (xin > 20.f) ? xin : log1pf(__expf(xin));
        float v = sp * A;
#pragma unroll
        for (int off = 1; off < 64; off <<= 1) {
            float u = __shfl_up(v, off, 64);
            if (lane6 >= off) v += u;
        }
        if (lane6 == 63) wsum[w] = v;
        __syncthreads();
        float add = 0.f;
        for (int wv = 0; wv < w; ++wv) add += wsum[wv];
        float cumv = v + add;
        float cl = wsum[0] + wsum[1] + wsum[2] + wsum[3];
        if ((t & 31) == 31) cumS8[t >> 5] = cumv;
        if (wr_meta) {
            cum[(size_t)bzh * CS + t] = cumv;
            cA[(size_t)bzh * CS + t] = sp * xs;
        }
        // --- x convert: xc (f16, *dtf*decay*xs*Bs) -> LDS; raw -> x8 ---
        float cBv = sp * __expf(cl - cumv) * xs * Bs;
        int xi[16] = {xw0.x, xw0.y, xw0.z, xw0.w, xw1.x, xw1.y, xw1.z, xw1.w,
                      xw2.x, xw2.y, xw2.z, xw2.w, xw3.x, xw3.y, xw3.z, xw3.w};
        signed char pk[16];
#pragma unroll
        for (int pl = 0; pl < 16; ++pl) {
            xcS[pl * XCB_PITCH + t] = (_Float16)((float)xi[pl] * cBv);
            pk[pl] = (signed char)xi[pl];
        }
        if (wr_x8)
            *(int4*)(x8 + ((size_t)(b * LSEQ + z * CS + t) * H + h) * PDIM + pq * 16) = *(int4*)pk;
        // --- prefetch z+1 (in flight across barrier + MFMA) ---
        if (z + 1 < NC) {
            rawv = (float)dt[(size_t)(b * LSEQ + (z + 1) * CS + t) * H + h];
            const int* xp = xq + ((size_t)(b * LSEQ + (z + 1) * CS + t) * H + h) * PDIM + pq * 16;
            xw0 = *(const int4*)xp; xw1 = *(const int4*)(xp + 4);
            xw2 = *(const int4*)(xp + 8); xw3 = *(const int4*)(xp + 12);
        }
        __syncthreads();
        // --- states MFMA (16p x 16n per wave) ---
        floatx4 accz = {};
        const _Float16* ab = xcS + m * XCB_PITCH;
        const _Float16* bb = Bt16T + ((size_t)(bz * 8 + ntg) * 32) * 128 + m * 8;
        for (int kk = 0; kk < 8; ++kk) {
            if (cl - cumS8[kk] < -30.f) continue;   // chunk underflows fp16 -> exact 0
            half8 a = *(const half8*)(ab + kk * 32 + q * 8);
            half8 bf = *(const half8*)(bb + (size_t)(kk * 4 + q) * 128);
            accz = __builtin_amdgcn_mfma_f32_16x16x32_f16(a, bf, accz, 0, 0, 0);
        }
        // --- scan: emit prev-state (f16/16), update carry ---
        float dz = __expf(cl);
        size_t sbase = (size_t)bzh * 8192 + (size_t)(pq * 16 + ntg * 2 + (m >> 3)) * 128 + (m & 7);
#pragma unroll
        for (int rr = 0; rr < 4; ++rr) {
            statesHT[sbase + (q * 4 + rr) * 8] = (_Float16)(carry[rr] * 0.0625f);
            carry[rr] = dz * carry[rr] + accz[rr];
        }
    }
}

// kC: fused inter+intra+D per (b,z,h); xTdt rebuilt in LDS from x8.
#define XT_PITCH 136    // halfs; 272B row -> 16B-aligned, rotating banks
__global__ __launch_bounds__(256) void kC(
    const signed char* __restrict__ x8, const int* __restrict__ qD,
    const float* __restrict__ cum, const float* __restrict__ cA,
    const _Float16* __restrict__ CBh, const _Float16* __restrict__ C16T,
    const _Float16* __restrict__ statesHT,
    const float* __restrict__ Cs_p, const float* __restrict__ xs_p, const float* __restrict__ Ds_p,
    float* __restrict__ out)
{
    __shared__ float cumL[CS];
    __shared__ __align__(16) char smem[4 * 32 * XT_PITCH * 2];   // 34816B: xT, later ep
    _Float16* xT = (_Float16*)smem;
    float (*ep)[65] = (float(*)[65])smem;                        // 33280B alias
    int t = threadIdx.x;
    int h = blockIdx.x & 31, z = (blockIdx.x >> 5) & 7, b = blockIdx.x >> 8;
    int bz = b * NC + z, bzh = bz * H + h;
    cumL[t] = cum[(size_t)bzh * CS + t];
    float cav = cA[(size_t)bzh * CS + t];

    // --- phase 1: x8 row t -> xT[p][s] * (dtf*xs), tiled f16 ---
    {
        const signed char* xrow = x8 + ((size_t)(b * LSEQ + z * CS + t) * H + h) * PDIM;
        int s8 = t >> 3, sj = t & 7;
        int rw[4] = {((const int4*)xrow)->x, 0, 0, 0};
        int4 r4 = *(const int4*)xrow;
        int4 r5 = *(const int4*)(xrow + 16);
        int4 r6 = *(const int4*)(xrow + 32);
        int4 r7 = *(const int4*)(xrow + 48);
        int words[16] = {r4.x, r4.y, r4.z, r4.w, r5.x, r5.y, r5.z, r5.w,
                         r6.x, r6.y, r6.z, r6.w, r7.x, r7.y, r7.z, r7.w};
        (void)rw;
#pragma unroll
        for (int wi = 0; wi < 16; ++wi) {
            int wv = words[wi];
#pragma unroll
            for (int bi = 0; bi < 4; ++bi) {
                int p = wi * 4 + bi;
                int val = (wv << (24 - 8 * bi)) >> 24;
                xT[((p >> 4) * 32 + s8) * XT_PITCH + (p & 15) * 8 + sj] =
                    (_Float16)((float)val * cav);
            }
        }
    }
    __syncthreads();

    int w = t >> 6, lane = t & 63, m = lane & 15, q = lane >> 4;
    floatx4 acc[4][4] = {};   // [j][pt], l16 = 4*j + w

    // ---- inter phase: acc = C_raw @ (prev/16) ----
    const _Float16* shb = statesHT + (size_t)bzh * 8192 + m * 8;
    const _Float16* cbase = C16T + (size_t)bz * 16 * 16 * 128 + m * 8;
    bool interact[4];
#pragma unroll
    for (int j = 0; j < 4; ++j) interact[j] = (cumL[(4 * j + w) * 16] > -80.f);
    for (int kk = 0; kk < 4; ++kk) {
        int n8 = kk * 4 + q;
        half8 bf[4];
#pragma unroll
        for (int pt = 0; pt < 4; ++pt)
            bf[pt] = *(const half8*)(shb + (pt * 16 + n8) * 128);
#pragma unroll
        for (int j = 0; j < 4; ++j) {
            if (!interact[j]) continue;
            half8 ha = *(const half8*)(cbase + ((size_t)(4 * j + w) * 16 + n8) * 128);
#pragma unroll
            for (int pt = 0; pt < 4; ++pt)
                acc[j][pt] = __builtin_amdgcn_mfma_f32_16x16x32_f16(ha, bf[pt], acc[j][pt], 0, 0, 0);
        }
    }
    float Cs16 = (*Cs_p) * 16.0f;
#pragma unroll
    for (int j = 0; j < 4; ++j)
#pragma unroll
        for (int r = 0; r < 4; ++r) {
            float e = __expf(cumL[(4 * j + w) * 16 + q * 4 + r]) * Cs16;
#pragma unroll
            for (int pt = 0; pt < 4; ++pt) acc[j][pt][r] *= e;
        }

    // ---- intra phase ----
    const _Float16* cbtb = CBh + (size_t)bz * 16 * 32 * 128 + m * 8;
    for (int kk = 0; kk < 8; ++kk) {
        int jmin = (2 * kk - w + 3) >> 2;
        if (jmin < 0) jmin = 0;
        if (jmin > 3) continue;
        int s8 = kk * 4 + q;
        half8 bf[4];
#pragma unroll
        for (int pt = 0; pt < 4; ++pt)
            bf[pt] = *(const half8*)(xT + (size_t)(pt * 32 + s8) * XT_PITCH + m * 8);
#pragma unroll
        for (int j = jmin; j < 4; ++j) {
            int l16 = 4 * j + w;
            if (cumL[l16 * 16] - cumL[kk * 32 + 31] < -30.f) continue;
            int lA = l16 * 16 + m;
            float cum_l = cumL[lA];
            half8 cb8 = *(const half8*)(cbtb + ((size_t)l16 * 32 + s8) * 128);
            half8 a;
#pragma unroll
            for (int jj = 0; jj < 8; ++jj) {
                int s = kk * 32 + q * 8 + jj;
                float wv = (float)cb8[jj] * __expf(cum_l - cumL[s]);
                a[jj] = (_Float16)((s <= lA) ? wv : 0.f);
            }
#pragma unroll
            for (int pt = 0; pt < 4; ++pt)
                acc[j][pt] = __builtin_amdgcn_mfma_f32_16x16x32_f16(a, bf[pt], acc[j][pt], 0, 0, 0);
        }
    }

    // ---- epilogue: LDS transpose (aliases xT) -> coalesced float4 out, + D*x ----
    float xsDf = (*xs_p) * ((float)qD[h] * (*Ds_p));
    __syncthreads();   // xT dead from here; smem becomes ep
#pragma unroll
    for (int pass = 0; pass < 2; ++pass) {
#pragma unroll
        for (int jj = 0; jj < 2; ++jj) {
            int j = pass * 2 + jj;
            int lbase = (((4 * j + w) * 16) & 127) + q * 4;
#pragma unroll
            for (int r = 0; r < 4; ++r)
#pragma unroll
                for (int pt = 0; pt < 4; ++pt)
                    ep[lbase + r][pt * 16 + m] = acc[j][pt][r];
        }
        __syncthreads();
        int lloc = t >> 1;
        int l = pass * 128 + lloc;
        size_t go = ((size_t)(b * LSEQ + z * CS + l) * H + h) * PDIM + (t & 1) * 32;
        const float* er = &ep[lloc][(t & 1) * 32];
        const signed char* xp8 = x8 + go;
#pragma unroll
        for (int it = 0; it < 8; ++it) {
            int xw = *(const int*)(xp8 + it * 4);
            floatx4 vv;
            vv[0] = er[it * 4 + 0] + (float)((xw << 24) >> 24) * xsDf;
            vv[1] = er[it * 4 + 1] + (float)((xw << 16) >> 24) * xsDf;
            vv[2] = er[it * 4 + 2] + (float)((xw << 8) >> 24) * xsDf;
            vv[3] = er[it * 4 + 3] + (float)(xw >> 24) * xsDf;
            *(floatx4*)(out + go + it * 4) = vv;
        }
        __syncthreads();
    }
}

extern "C" void kernel_launch(void* const* d_in, const int* in_sizes, int n_in,
                              void* d_out, int out_size, void* d_ws, size_t ws_size,
                              hipStream_t stream)
{
    const int* xq = (const int*)d_in[0];
    const int* dt = (const int*)d_in[1];
    const int* Bm = (const int*)d_in[2];
    const int* Cm = (const int*)d_in[3];
    const int* qA = (const int*)d_in[4];
    const int* qD = (const int*)d_in[5];
    const float* dt_bias = (const float*)d_in[6];
    const float* A_scale = (const float*)d_in[7];
    const float* D_scale = (const float*)d_in[8];
    const float* dt_scale = (const float*)d_in[9];
    const float* x_scale = (const float*)d_in[10];
    const float* B_scale = (const float*)d_in[11];
    const float* C_scale = (const float*)d_in[12];
    float* out = (float*)d_out;

    char* ws = (char*)d_ws;
    float* cum          = (float*)(ws);
    float* cA           = (float*)(ws + 524288);
    _Float16* CBh       = (_Float16*)(ws + 1048576);
    _Float16* statesHT  = (_Float16*)(ws + 3145728);
    _Float16* Bt16T     = (_Float16*)(ws + 11534336);
    _Float16* C16T      = (_Float16*)(ws + 12582912);
    signed char* x8     = (signed char*)(ws + 13631488);

    kA<<<dim3(416), dim3(256), 0, stream>>>(Bm, Cm, B_scale, C_scale, CBh, Bt16T, C16T);
    kB<<<dim3(512), dim3(256), 0, stream>>>(dt, qA, dt_bias, A_scale, dt_scale,
                                            xq, x_scale, B_scale, Bt16T,
                                            cum, cA, x8, statesHT);
    kC<<<dim3(512), dim3(256), 0, stream>>>(x8, qD, cum, cA, CBh, C16T, statesHT,
                                            C_scale, x_scale, D_scale, out);
}

// Round 7
// 169.018 us; speedup vs baseline: 1.3763x; 1.3763x over previous
//
#include <hip/hip_runtime.h>
#include <math.h>

#define BB 2
#define LSEQ 2048
#define H 32
#define PDIM 64
#define NDIM 128
#define CS 256
#define NC 8

typedef _Float16 half8 __attribute__((ext_vector_type(8)));
typedef _Float16 half4 __attribute__((ext_vector_type(4)));
typedef float floatx4 __attribute__((ext_vector_type(4)));

// ---------------- ws layout (bytes) ----------------
// cum      : f32 [bz=16][H][CS]               @ 0         (512 KB)
// cdecay   : f32 [bz][H]                      @ 524288    (2 KB)
// CBh      : f16 [bz][l16=16][s8=32][16][8]   @ 526336    (2 MB)  MFMA-tiled, causal only
// statesF16: f16 [bzh][8192] tiled /16        @ 2623488   (8 MB)  per-chunk states
// statesHT : f16 [bzh][8192] tiled /16        @ 11012096  (8 MB)  prev-state (post-scan)
// xTdtT    : f16 [bzh][p16=4][s8=32][16][8]   @ 19400704  (16 MB) x*dtf*xs, tiled
// Bt16T    : f16 [bz][n16=8][s8=32][16][8]    @ 36177920  (1 MB)
// C16T     : f16 [bz][l16=16][n8=16][16][8]   @ 37226496  (1 MB)
// x8       : i8  [b][l][h][p]                 @ 38275072  (8 MB)

__device__ __forceinline__ int dot4i8(int a, int b, int c) {
#if __has_builtin(__builtin_amdgcn_sdot4)
    return __builtin_amdgcn_sdot4(a, b, c, false);
#else
    c += ((a << 24) >> 24) * ((b << 24) >> 24);
    c += ((a << 16) >> 24) * ((b << 16) >> 24);
    c += ((a << 8) >> 24) * ((b << 8) >> 24);
    c += (a >> 24) * (b >> 24);
    return c;
#endif
}

// kA: CBh Gram (causal 64x64 tiles, f16) + Bt16T/C16T prep
__global__ __launch_bounds__(256) void kA(
    const int* __restrict__ Bm, const int* __restrict__ Cm,
    const float* __restrict__ Bs_p, const float* __restrict__ Cs_p,
    _Float16* __restrict__ CBh, _Float16* __restrict__ Bt16T, _Float16* __restrict__ C16T)
{
    __shared__ int Bi[64][33];
    __shared__ int Ci[64][33];
    int t = threadIdx.x;
    int r = blockIdx.x % 26;
    int zz = blockIdx.x / 26;
    int z = zz & 7, b = zz >> 3;
    int bz = b * NC + z;
    if (r < 10) {
        const int LT[10] = {0,1,1,2,2,2,3,3,3,3};
        const int ST[10] = {0,0,1,0,1,2,0,1,2,3};
        int l0 = LT[r] * 64, s0 = ST[r] * 64;
        const int* Bp = Bm + (size_t)(b * LSEQ + z * CS + s0) * NDIM;
        const int* Cp = Cm + (size_t)(b * LSEQ + z * CS + l0) * NDIM;
        for (int i = t; i < 64 * 32; i += 256) {
            int rr = i >> 5, k = i & 31;
            const int* sb = Bp + rr * NDIM + k * 4;
            const int* sc = Cp + rr * NDIM + k * 4;
            Bi[rr][k] = (sb[0] & 255) | ((sb[1] & 255) << 8) | ((sb[2] & 255) << 16) | ((sb[3] & 255) << 24);
            Ci[rr][k] = (sc[0] & 255) | ((sc[1] & 255) << 8) | ((sc[2] & 255) << 16) | ((sc[3] & 255) << 24);
        }
        __syncthreads();
        float cbscale = (*Bs_p) * (*Cs_p);
        int ll = t & 63, lg = t >> 6;
        int acc[16];
#pragma unroll
        for (int i = 0; i < 16; ++i) acc[i] = 0;
        for (int k = 0; k < 32; ++k) {
            int cw = Ci[ll][k];
#pragma unroll
            for (int si = 0; si < 16; ++si)
                acc[si] = dot4i8(cw, Bi[lg * 16 + si][k], acc[si]);
        }
        int l = l0 + ll;
        int l16 = l >> 4, lm = l & 15;
        int sb8 = (s0 + lg * 16) >> 3;
        _Float16* bp = CBh + ((size_t)(bz * 16 + l16) * 32 + sb8) * 128 + lm * 8;
#pragma unroll
        for (int g = 0; g < 2; ++g) {
            half8 v;
#pragma unroll
            for (int i = 0; i < 8; ++i) v[i] = (_Float16)((float)acc[g * 8 + i] * cbscale);
            *(half8*)(bp + g * 128) = v;
        }
    } else {
        int slice = r - 10;   // 0..15
        {   // C16T: l16 = slice
            int lm = t >> 4, n8 = t & 15;
            const int* cp = Cm + (size_t)(b * LSEQ + z * CS + slice * 16 + lm) * NDIM + n8 * 8;
            int4 c0 = *(const int4*)cp;
            int4 c1 = *(const int4*)(cp + 4);
            half8 v;
            v[0] = (_Float16)(float)c0.x; v[1] = (_Float16)(float)c0.y;
            v[2] = (_Float16)(float)c0.z; v[3] = (_Float16)(float)c0.w;
            v[4] = (_Float16)(float)c1.x; v[5] = (_Float16)(float)c1.y;
            v[6] = (_Float16)(float)c1.z; v[7] = (_Float16)(float)c1.w;
            *(half8*)(C16T + ((size_t)(bz * 16 + slice) * 16 + n8) * 128 + lm * 8) = v;
        }
        {   // Bt16T transpose: n16 = slice&7, s-half = slice>>3
            int nm = t & 15, s8l = t >> 4;
            int n16 = slice & 7, s8 = (slice >> 3) * 16 + s8l;
            const int* bp = Bm + (size_t)(b * LSEQ + z * CS + s8 * 8) * NDIM + n16 * 16 + nm;
            half8 v;
#pragma unroll
            for (int j = 0; j < 8; ++j) v[j] = (_Float16)(float)bp[(size_t)j * NDIM];
            *(half8*)(Bt16T + ((size_t)(bz * 8 + n16) * 32 + s8) * 128 + nm * 8) = v;
        }
    }
}

// k013: fused softplus/cumsum + x transpose + states MFMA.
// grid 1024: one block per (b,z,h,p-half); states emitted f16/16 in tiled layout.
#define XC_PITCH 132
__global__ __launch_bounds__(256) void k013(
    const int* __restrict__ dt, const int* __restrict__ qA, const float* __restrict__ dt_bias,
    const float* __restrict__ A_scale_p, const float* __restrict__ dt_scale_p,
    const int* __restrict__ xq, const float* __restrict__ xs_p, const float* __restrict__ Bs_p,
    const _Float16* __restrict__ Bt16T,
    float* __restrict__ cum, float* __restrict__ cdecay,
    _Float16* __restrict__ xTdtT, signed char* __restrict__ x8,
    _Float16* __restrict__ statesF16)
{
    __shared__ float cumS[CS];
    __shared__ float cA[CS], cB[CS];
    __shared__ float wsum[4];
    __shared__ _Float16 xcS[2 * 32 * XC_PITCH];
    int t = threadIdx.x;
    int half = blockIdx.x & 1;
    int h = (blockIdx.x >> 1) & 31, z = (blockIdx.x >> 6) & 7, b = blockIdx.x >> 9;
    int bz = b * NC + z, bzh = bz * H + h;
    int lane6 = t & 63, w = t >> 6;

    // --- softplus + wave-shuffle inclusive scan ---
    float A = -__expf((float)qA[h] * (*A_scale_p));
    float raw = (float)dt[(size_t)(b * LSEQ + z * CS + t) * H + h];
    float xin = raw * (*dt_scale_p) + dt_bias[h];
    float sp = (xin > 20.f) ? xin : log1pf(__expf(xin));
    float v = sp * A;
#pragma unroll
    for (int off = 1; off < 64; off <<= 1) {
        float u = __shfl_up(v, off, 64);
        if (lane6 >= off) v += u;
    }
    if (lane6 == 63) wsum[w] = v;
    __syncthreads();
    float add = 0.f;
    for (int wv = 0; wv < w; ++wv) add += wsum[wv];
    float cumv = v + add;
    float cl = wsum[0] + wsum[1] + wsum[2] + wsum[3];
    float xs = *xs_p;
    if (half == 0) {
        cum[(size_t)bzh * CS + t] = cumv;
        if (t == 0) cdecay[bzh] = __expf(cl);
    }
    cumS[t] = cumv;
    cA[t] = sp * xs;
    cB[t] = sp * __expf(cl - cumv) * xs * (*Bs_p);
    __syncthreads();

    // --- x load/transpose (32 of 64 p): xTdt->global, xc->LDS, x8->global ---
    int s8 = t & 31, pq = t >> 5;
    const int* xb = xq + ((size_t)(b * LSEQ + z * CS) * H + h) * PDIM + half * 32 + pq * 4;
    signed char* x8b = x8 + ((size_t)(b * LSEQ + z * CS) * H + h) * PDIM + half * 32 + pq * 4;
    {
        half8 va[4], vc[4];
#pragma unroll
        for (int j = 0; j < 8; ++j) {
            int s = s8 * 8 + j;
            int4 w4 = *(const int4*)(xb + (size_t)s * (H * PDIM));
            float a = cA[s], c = cB[s];
            signed char pk[4];
#define CVT(PL, V) { float xv = (float)(V); va[PL][j] = (_Float16)(xv * a); vc[PL][j] = (_Float16)(xv * c); pk[PL] = (signed char)(V); }
            CVT(0, w4.x) CVT(1, w4.y) CVT(2, w4.z) CVT(3, w4.w)
#undef CVT
            *(int*)(x8b + (size_t)s * (H * PDIM)) = *(int*)pk;
        }
#pragma unroll
        for (int pl = 0; pl < 4; ++pl) {
            int ploc = pq * 4 + pl;
            int p16l = ploc >> 4, pm = ploc & 15;
            *(half8*)(xTdtT + ((size_t)(bzh * 4 + half * 2 + p16l) * 32 + s8) * 128 + pm * 8) = va[pl];
            *(half8*)(xcS + (p16l * 32 + s8) * XC_PITCH + pm * 8) = vc[pl];
        }
    }
    __syncthreads();

    // --- states MFMA: wave w -> p16l = w&1, nt-half = w>>1 ---
    int m = lane6 & 15, q = lane6 >> 4;
    int p16l = w & 1, ntb = (w >> 1) * 4;
    const _Float16* abase = xcS + (p16l * 32) * XC_PITCH + m * 8;
    const _Float16* bbase = Bt16T + ((size_t)(bz * 8 + ntb) * 32) * 128 + m * 8;
    floatx4 acc[4] = {};
    for (int kk = 0; kk < 8; ++kk) {
        if (cl - cumS[kk * 32 + 31] < -30.f) continue;   // fp16-exact-0 chunk skip
        int s8k = kk * 4 + q;
        half8 a = *(const half8*)(abase + s8k * XC_PITCH);
#pragma unroll
        for (int i = 0; i < 4; ++i) {
            half8 bf = *(const half8*)(bbase + ((size_t)i * 32 + s8k) * 128);
            acc[i] = __builtin_amdgcn_mfma_f32_16x16x32_f16(a, bf, acc[i], 0, 0, 0);
        }
    }
    // store f16/16 in tiled (statesHT-compatible) layout
    int p16 = half * 2 + p16l;
    _Float16* sb = statesF16 + (size_t)bzh * 8192;
#pragma unroll
    for (int i = 0; i < 4; ++i)
#pragma unroll
        for (int rr = 0; rr < 4; ++rr)
            sb[(size_t)(p16 * 16 + (ntb + i) * 2 + (m >> 3)) * 128 + (q * 4 + rr) * 8 + (m & 7)] =
                (_Float16)(acc[i][rr] * 0.0625f);
}

// k4: sequential inter-chunk scan on flat tiled f16 arrays (same index in/out)
__global__ __launch_bounds__(256) void k4_scan(
    const float* __restrict__ cdecay, const _Float16* __restrict__ statesF16,
    _Float16* __restrict__ statesHT)
{
    int idx = blockIdx.x * 256 + threadIdx.x;
    int off4 = (idx & 2047) * 4;
    int h = (idx >> 11) & 31, b = idx >> 16;
    floatx4 carry = {};
    for (int z = 0; z < NC; ++z) {
        int bzh = (b * NC + z) * H + h;
        half4 v4 = *(const half4*)(statesF16 + (size_t)bzh * 8192 + off4);
        float d = cdecay[bzh];
        half4 o;
#pragma unroll
        for (int i = 0; i < 4; ++i) o[i] = (_Float16)carry[i];
        *(half4*)(statesHT + (size_t)bzh * 8192 + off4) = o;
#pragma unroll
        for (int i = 0; i < 4; ++i) carry[i] = d * carry[i] + (float)v4[i];
    }
}

// k56: fused inter+intra+D. grid 1024: (b,z,h) x p-half (2 of 4 p16 tiles).
__global__ __launch_bounds__(256) void k56(
    const signed char* __restrict__ x8, const int* __restrict__ qD,
    const float* __restrict__ cum, const _Float16* __restrict__ CBh,
    const _Float16* __restrict__ xTdtT, const _Float16* __restrict__ C16T,
    const _Float16* __restrict__ statesHT,
    const float* __restrict__ Cs_p, const float* __restrict__ xs_p, const float* __restrict__ Ds_p,
    float* __restrict__ out)
{
    __shared__ float cumL[CS];
    __shared__ float ep[128][33];
    int t = threadIdx.x;
    int ph = blockIdx.x & 1;
    int h = (blockIdx.x >> 1) & 31, z = (blockIdx.x >> 6) & 7, b = blockIdx.x >> 9;
    int bz = b * NC + z, bzh = bz * H + h;
    cumL[t] = cum[(size_t)bzh * CS + t];
    __syncthreads();
    int w = t >> 6, lane = t & 63, m = lane & 15, q = lane >> 4;
    floatx4 acc[4][2] = {};   // [j][pt_loc], l16 = 4*j + w, pt = ph*2 + pt_loc

    // ---- inter phase: acc = C_raw @ (prev/16) ----
    const _Float16* shb = statesHT + (size_t)bzh * 8192 + m * 8;
    const _Float16* cbase = C16T + (size_t)bz * 16 * 16 * 128 + m * 8;
    bool interact[4];
#pragma unroll
    for (int j = 0; j < 4; ++j) interact[j] = (cumL[(4 * j + w) * 16] > -80.f);
    for (int kk = 0; kk < 4; ++kk) {
        int n8 = kk * 4 + q;
        half8 bf[2];
#pragma unroll
        for (int pt = 0; pt < 2; ++pt)
            bf[pt] = *(const half8*)(shb + ((ph * 2 + pt) * 16 + n8) * 128);
#pragma unroll
        for (int j = 0; j < 4; ++j) {
            if (!interact[j]) continue;
            half8 ha = *(const half8*)(cbase + ((size_t)(4 * j + w) * 16 + n8) * 128);
#pragma unroll
            for (int pt = 0; pt < 2; ++pt)
                acc[j][pt] = __builtin_amdgcn_mfma_f32_16x16x32_f16(ha, bf[pt], acc[j][pt], 0, 0, 0);
        }
    }
    float Cs16 = (*Cs_p) * 16.0f;
#pragma unroll
    for (int j = 0; j < 4; ++j)
#pragma unroll
        for (int r = 0; r < 4; ++r) {
            float e = __expf(cumL[(4 * j + w) * 16 + q * 4 + r]) * Cs16;
#pragma unroll
            for (int pt = 0; pt < 2; ++pt) acc[j][pt][r] *= e;
        }

    // ---- intra phase (compile-time j bounds; predicate with continue) ----
    const _Float16* cbtb = CBh + (size_t)bz * 16 * 32 * 128 + m * 8;
    const _Float16* xb = xTdtT + (size_t)bzh * 4 * 32 * 128 + m * 8;
    for (int kk = 0; kk < 8; ++kk) {
        int jmin = (2 * kk - w + 3) >> 2;
        if (jmin < 0) jmin = 0;
        if (jmin > 3) continue;
        int s8 = kk * 4 + q;
        half8 bf[2];
#pragma unroll
        for (int pt = 0; pt < 2; ++pt)
            bf[pt] = *(const half8*)(xb + ((size_t)((ph * 2 + pt) * 32 + s8)) * 128);
#pragma unroll
        for (int j = 0; j < 4; ++j) {
            if (j < jmin) continue;
            int l16 = 4 * j + w;
            if (cumL[l16 * 16] - cumL[kk * 32 + 31] < -30.f) continue;
            int lA = l16 * 16 + m;
            float cum_l = cumL[lA];
            half8 cb8 = *(const half8*)(cbtb + ((size_t)l16 * 32 + s8) * 128);
            half8 a;
#pragma unroll
            for (int jj = 0; jj < 8; ++jj) {
                int s = kk * 32 + q * 8 + jj;
                float wv = (float)cb8[jj] * __expf(cum_l - cumL[s]);
                a[jj] = (_Float16)((s <= lA) ? wv : 0.f);
            }
#pragma unroll
            for (int pt = 0; pt < 2; ++pt)
                acc[j][pt] = __builtin_amdgcn_mfma_f32_16x16x32_f16(a, bf[pt], acc[j][pt], 0, 0, 0);
        }
    }

    // ---- epilogue: LDS transpose -> coalesced float4 out, + D*x ----
    float xsDf = (*xs_p) * ((float)qD[h] * (*Ds_p));
    __syncthreads();
#pragma unroll
    for (int pass = 0; pass < 2; ++pass) {
#pragma unroll
        for (int jj = 0; jj < 2; ++jj) {
            int j = pass * 2 + jj;
            int lbase = (((4 * j + w) * 16) & 127) + q * 4;
#pragma unroll
            for (int r = 0; r < 4; ++r)
#pragma unroll
                for (int pt = 0; pt < 2; ++pt)
                    ep[lbase + r][pt * 16 + m] = acc[j][pt][r];
        }
        __syncthreads();
        int lloc = t >> 1;
        int l = pass * 128 + lloc;
        size_t go = ((size_t)(b * LSEQ + z * CS + l) * H + h) * PDIM + ph * 32 + (t & 1) * 16;
        const float* er = &ep[lloc][(t & 1) * 16];
        const signed char* xp8 = x8 + go;
#pragma unroll
        for (int it = 0; it < 4; ++it) {
            int xw = *(const int*)(xp8 + it * 4);
            floatx4 vv;
            vv[0] = er[it * 4 + 0] + (float)((xw << 24) >> 24) * xsDf;
            vv[1] = er[it * 4 + 1] + (float)((xw << 16) >> 24) * xsDf;
            vv[2] = er[it * 4 + 2] + (float)((xw << 8) >> 24) * xsDf;
            vv[3] = er[it * 4 + 3] + (float)(xw >> 24) * xsDf;
            *(floatx4*)(out + go + it * 4) = vv;
        }
        __syncthreads();
    }
}

extern "C" void kernel_launch(void* const* d_in, const int* in_sizes, int n_in,
                              void* d_out, int out_size, void* d_ws, size_t ws_size,
                              hipStream_t stream)
{
    const int* xq = (const int*)d_in[0];
    const int* dt = (const int*)d_in[1];
    const int* Bm = (const int*)d_in[2];
    const int* Cm = (const int*)d_in[3];
    const int* qA = (const int*)d_in[4];
    const int* qD = (const int*)d_in[5];
    const float* dt_bias = (const float*)d_in[6];
    const float* A_scale = (const float*)d_in[7];
    const float* D_scale = (const float*)d_in[8];
    const float* dt_scale = (const float*)d_in[9];
    const float* x_scale = (const float*)d_in[10];
    const float* B_scale = (const float*)d_in[11];
    const float* C_scale = (const float*)d_in[12];
    float* out = (float*)d_out;

    char* ws = (char*)d_ws;
    float* cum           = (float*)(ws);
    float* cdecay        = (float*)(ws + 524288);
    _Float16* CBh        = (_Float16*)(ws + 526336);
    _Float16* statesF16  = (_Float16*)(ws + 2623488);
    _Float16* statesHT   = (_Float16*)(ws + 11012096);
    _Float16* xTdtT      = (_Float16*)(ws + 19400704);
    _Float16* Bt16T      = (_Float16*)(ws + 36177920);
    _Float16* C16T       = (_Float16*)(ws + 37226496);
    signed char* x8      = (signed char*)(ws + 38275072);

    kA<<<dim3(416), dim3(256), 0, stream>>>(Bm, Cm, B_scale, C_scale, CBh, Bt16T, C16T);
    k013<<<dim3(1024), dim3(256), 0, stream>>>(dt, qA, dt_bias, A_scale, dt_scale,
                                               xq, x_scale, B_scale, Bt16T,
                                               cum, cdecay, xTdtT, x8, statesF16);
    k4_scan<<<dim3(512), dim3(256), 0, stream>>>(cdecay, statesF16, statesHT);
    k56<<<dim3(1024), dim3(256), 0, stream>>>(x8, qD, cum, CBh, xTdtT, C16T, statesHT,
                                              C_scale, x_scale, D_scale, out);
}

// Round 8
// 156.106 us; speedup vs baseline: 1.4901x; 1.0827x over previous
//
#include <hip/hip_runtime.h>
#include <math.h>

#define BB 2
#define LSEQ 2048
#define H 32
#define PDIM 64
#define NDIM 128
#define CS 256
#define NC 8

typedef _Float16 half8 __attribute__((ext_vector_type(8)));
typedef _Float16 half4 __attribute__((ext_vector_type(4)));
typedef float floatx4 __attribute__((ext_vector_type(4)));

// ---------------- ws layout (bytes) ----------------
// cum      : f32 [bz=16][H][CS]               @ 0         (512 KB)
// cA       : f32 [bz][H][CS]  (dtf*xs)        @ 524288    (512 KB)
// cdecay   : f32 [bz][H]                      @ 1048576   (2 KB)
// CBh      : f16 [bz][l16=16][s8=32][16][8]   @ 1050624   (2 MB)  MFMA-tiled, causal only
// statesF16: f16 [bzh][8192] tiled /16        @ 3147776   (8 MB)
// statesHT : f16 [bzh][8192] tiled /16        @ 11536384  (8 MB)  prev-state (post-scan)
// Bt16T    : f16 [bz][n16=8][s8=32][16][8]    @ 19924992  (1 MB)
// C16T     : f16 [bz][l16=16][n8=16][16][8]   @ 20973568  (1 MB)
// x8       : i8  [b][l][h][p]                 @ 22022144  (8 MB)

__device__ __forceinline__ int dot4i8(int a, int b, int c) {
#if __has_builtin(__builtin_amdgcn_sdot4)
    return __builtin_amdgcn_sdot4(a, b, c, false);
#else
    c += ((a << 24) >> 24) * ((b << 24) >> 24);
    c += ((a << 16) >> 24) * ((b << 16) >> 24);
    c += ((a << 8) >> 24) * ((b << 8) >> 24);
    c += (a >> 24) * (b >> 24);
    return c;
#endif
}

// kA: CBh Gram (causal 64x64 tiles, f16) + Bt16T/C16T prep
__global__ __launch_bounds__(256) void kA(
    const int* __restrict__ Bm, const int* __restrict__ Cm,
    const float* __restrict__ Bs_p, const float* __restrict__ Cs_p,
    _Float16* __restrict__ CBh, _Float16* __restrict__ Bt16T, _Float16* __restrict__ C16T)
{
    __shared__ int Bi[64][33];
    __shared__ int Ci[64][33];
    int t = threadIdx.x;
    int r = blockIdx.x % 26;
    int zz = blockIdx.x / 26;
    int z = zz & 7, b = zz >> 3;
    int bz = b * NC + z;
    if (r < 10) {
        const int LT[10] = {0,1,1,2,2,2,3,3,3,3};
        const int ST[10] = {0,0,1,0,1,2,0,1,2,3};
        int l0 = LT[r] * 64, s0 = ST[r] * 64;
        const int* Bp = Bm + (size_t)(b * LSEQ + z * CS + s0) * NDIM;
        const int* Cp = Cm + (size_t)(b * LSEQ + z * CS + l0) * NDIM;
        for (int i = t; i < 64 * 32; i += 256) {
            int rr = i >> 5, k = i & 31;
            const int* sb = Bp + rr * NDIM + k * 4;
            const int* sc = Cp + rr * NDIM + k * 4;
            Bi[rr][k] = (sb[0] & 255) | ((sb[1] & 255) << 8) | ((sb[2] & 255) << 16) | ((sb[3] & 255) << 24);
            Ci[rr][k] = (sc[0] & 255) | ((sc[1] & 255) << 8) | ((sc[2] & 255) << 16) | ((sc[3] & 255) << 24);
        }
        __syncthreads();
        float cbscale = (*Bs_p) * (*Cs_p);
        int ll = t & 63, lg = t >> 6;
        int acc[16];
#pragma unroll
        for (int i = 0; i < 16; ++i) acc[i] = 0;
        for (int k = 0; k < 32; ++k) {
            int cw = Ci[ll][k];
#pragma unroll
            for (int si = 0; si < 16; ++si)
                acc[si] = dot4i8(cw, Bi[lg * 16 + si][k], acc[si]);
        }
        int l = l0 + ll;
        int l16 = l >> 4, lm = l & 15;
        int sb8 = (s0 + lg * 16) >> 3;
        _Float16* bp = CBh + ((size_t)(bz * 16 + l16) * 32 + sb8) * 128 + lm * 8;
#pragma unroll
        for (int g = 0; g < 2; ++g) {
            half8 v;
#pragma unroll
            for (int i = 0; i < 8; ++i) v[i] = (_Float16)((float)acc[g * 8 + i] * cbscale);
            *(half8*)(bp + g * 128) = v;
        }
    } else {
        int slice = r - 10;   // 0..15
        {   // C16T: l16 = slice
            int lm = t >> 4, n8 = t & 15;
            const int* cp = Cm + (size_t)(b * LSEQ + z * CS + slice * 16 + lm) * NDIM + n8 * 8;
            int4 c0 = *(const int4*)cp;
            int4 c1 = *(const int4*)(cp + 4);
            half8 v;
            v[0] = (_Float16)(float)c0.x; v[1] = (_Float16)(float)c0.y;
            v[2] = (_Float16)(float)c0.z; v[3] = (_Float16)(float)c0.w;
            v[4] = (_Float16)(float)c1.x; v[5] = (_Float16)(float)c1.y;
            v[6] = (_Float16)(float)c1.z; v[7] = (_Float16)(float)c1.w;
            *(half8*)(C16T + ((size_t)(bz * 16 + slice) * 16 + n8) * 128 + lm * 8) = v;
        }
        {   // Bt16T transpose: n16 = slice&7, s-half = slice>>3
            int nm = t & 15, s8l = t >> 4;
            int n16 = slice & 7, s8 = (slice >> 3) * 16 + s8l;
            const int* bp = Bm + (size_t)(b * LSEQ + z * CS + s8 * 8) * NDIM + n16 * 16 + nm;
            half8 v;
#pragma unroll
            for (int j = 0; j < 8; ++j) v[j] = (_Float16)(float)bp[(size_t)j * NDIM];
            *(half8*)(Bt16T + ((size_t)(bz * 8 + n16) * 32 + s8) * 128 + nm * 8) = v;
        }
    }
}

// k013: softplus/cumsum + COALESCED x load -> LDS transpose -> states MFMA.
// grid 512, one block per (b,z,h). No xTdt output (k56 rebuilds from x8).
// xcS pitched tile: off(p,s) = (p>>4)*4360 + (s>>3)*136 + (p&15)*8 + (s&7)
#define P16_STRIDE 4360   // 32*136 + 8 halfs: +8 skew keeps scatter <=2-way banked
__global__ __launch_bounds__(256) void k013(
    const int* __restrict__ dt, const int* __restrict__ qA, const float* __restrict__ dt_bias,
    const float* __restrict__ A_scale_p, const float* __restrict__ dt_scale_p,
    const int* __restrict__ xq, const float* __restrict__ xs_p, const float* __restrict__ Bs_p,
    const _Float16* __restrict__ Bt16T,
    float* __restrict__ cum, float* __restrict__ cAg, float* __restrict__ cdecay,
    signed char* __restrict__ x8, _Float16* __restrict__ statesF16)
{
    __shared__ float cumS[CS];
    __shared__ float cB[CS];
    __shared__ float wsum[4];
    __shared__ _Float16 xcS[3 * P16_STRIDE + 31 * 136 + 128];   // ~34.9 KB
    int t = threadIdx.x;
    int h = blockIdx.x & 31, z = (blockIdx.x >> 5) & 7, b = blockIdx.x >> 8;
    int bz = b * NC + z, bzh = bz * H + h;
    int lane6 = t & 63, w = t >> 6;

    // --- softplus + wave-shuffle inclusive scan ---
    float A = -__expf((float)qA[h] * (*A_scale_p));
    float raw = (float)dt[(size_t)(b * LSEQ + z * CS + t) * H + h];
    float xin = raw * (*dt_scale_p) + dt_bias[h];
    float sp = (xin > 20.f) ? xin : log1pf(__expf(xin));
    float v = sp * A;
#pragma unroll
    for (int off = 1; off < 64; off <<= 1) {
        float u = __shfl_up(v, off, 64);
        if (lane6 >= off) v += u;
    }
    if (lane6 == 63) wsum[w] = v;
    __syncthreads();
    float add = 0.f;
    for (int wv = 0; wv < w; ++wv) add += wsum[wv];
    float cumv = v + add;
    float cl = wsum[0] + wsum[1] + wsum[2] + wsum[3];
    float xs = *xs_p;
    cum[(size_t)bzh * CS + t] = cumv;
    cAg[(size_t)bzh * CS + t] = sp * xs;
    if (t == 0) cdecay[bzh] = __expf(cl);
    cumS[t] = cumv;
    cB[t] = sp * __expf(cl - cumv) * xs * (*Bs_p);
    __syncthreads();

    // --- coalesced x: lanes cover rows (16 lanes x 16B = full 256B row) ---
    int pq = t & 15, srow = t >> 4;
    const int* xb = xq + ((size_t)(b * LSEQ + z * CS) * H + h) * PDIM + pq * 4;
    signed char* x8b = x8 + ((size_t)(b * LSEQ + z * CS) * H + h) * PDIM + pq * 4;
    int p0 = pq * 4;
    int pbase = (p0 >> 4) * P16_STRIDE + ((p0 & 15) * 8);
    for (int j = 0; j < 16; ++j) {
        int s = j * 16 + srow;
        int4 w4 = *(const int4*)(xb + (size_t)s * (H * PDIM));
        float c = cB[s];
        int sbase = pbase + (s >> 3) * 136 + (s & 7);
        signed char pk[4];
        int xi[4] = {w4.x, w4.y, w4.z, w4.w};
#pragma unroll
        for (int pp = 0; pp < 4; ++pp) {
            xcS[sbase + pp * 8] = (_Float16)((float)xi[pp] * c);
            pk[pp] = (signed char)xi[pp];
        }
        *(int*)(x8b + (size_t)s * (H * PDIM)) = *(int*)pk;
    }
    __syncthreads();

    // --- states MFMA: wave w -> p16 tile w; 8 n-tiles ---
    int m = lane6 & 15, q = lane6 >> 4;
    const _Float16* abase = xcS + w * P16_STRIDE + m * 8;
    const _Float16* bbase = Bt16T + (size_t)(bz * 8) * 32 * 128 + m * 8;
    floatx4 acc[8] = {};
    for (int kk = 0; kk < 8; ++kk) {
        if (cl - cumS[kk * 32 + 31] < -30.f) continue;   // fp16-exact-0 chunk skip
        int s8k = kk * 4 + q;
        half8 a = *(const half8*)(abase + s8k * 136);
#pragma unroll
        for (int nt = 0; nt < 8; ++nt) {
            half8 bf = *(const half8*)(bbase + ((size_t)nt * 32 + s8k) * 128);
            acc[nt] = __builtin_amdgcn_mfma_f32_16x16x32_f16(a, bf, acc[nt], 0, 0, 0);
        }
    }
    // store f16/16 tiled: elem (p,n) -> ((p>>4)*16 + (n>>3))*128 + (p&15)*8 + (n&7)
    _Float16* sb = statesF16 + (size_t)bzh * 8192;
#pragma unroll
    for (int nt = 0; nt < 8; ++nt)
#pragma unroll
        for (int rr = 0; rr < 4; ++rr)
            sb[(size_t)(w * 16 + nt * 2 + (m >> 3)) * 128 + (q * 4 + rr) * 8 + (m & 7)] =
                (_Float16)(acc[nt][rr] * 0.0625f);
}

// k4: sequential inter-chunk scan on flat tiled f16 arrays (same index in/out)
__global__ __launch_bounds__(256) void k4_scan(
    const float* __restrict__ cdecay, const _Float16* __restrict__ statesF16,
    _Float16* __restrict__ statesHT)
{
    int idx = blockIdx.x * 256 + threadIdx.x;
    int off4 = (idx & 2047) * 4;
    int h = (idx >> 11) & 31, b = idx >> 16;
    floatx4 carry = {};
    for (int z = 0; z < NC; ++z) {
        int bzh = (b * NC + z) * H + h;
        half4 v4 = *(const half4*)(statesF16 + (size_t)bzh * 8192 + off4);
        float d = cdecay[bzh];
        half4 o;
#pragma unroll
        for (int i = 0; i < 4; ++i) o[i] = (_Float16)carry[i];
        *(half4*)(statesHT + (size_t)bzh * 8192 + off4) = o;
#pragma unroll
        for (int i = 0; i < 4; ++i) carry[i] = d * carry[i] + (float)v4[i];
    }
}

// k56: fused inter+intra+D per (b,z,h), grid 512. xTdt fragments rebuilt
// in LDS from x8 (coalesced); intra j-loop is compile-time-predicated (no spill).
#define XT_PITCH 136
__global__ __launch_bounds__(256) void k56(
    const signed char* __restrict__ x8, const int* __restrict__ qD,
    const float* __restrict__ cum, const float* __restrict__ cAg,
    const _Float16* __restrict__ CBh, const _Float16* __restrict__ C16T,
    const _Float16* __restrict__ statesHT,
    const float* __restrict__ Cs_p, const float* __restrict__ xs_p, const float* __restrict__ Ds_p,
    float* __restrict__ out)
{
    __shared__ float cumL[CS];
    __shared__ __align__(16) char smem[4 * 32 * XT_PITCH * 2];   // 34816B: xT, later ep
    _Float16* xT = (_Float16*)smem;
    float (*ep)[65] = (float(*)[65])smem;                        // 33280B alias
    int t = threadIdx.x;
    int h = blockIdx.x & 31, z = (blockIdx.x >> 5) & 7, b = blockIdx.x >> 8;
    int bz = b * NC + z, bzh = bz * H + h;
    cumL[t] = cum[(size_t)bzh * CS + t];
    float cav = cAg[(size_t)bzh * CS + t];

    // --- phase 1: x8 row t (coalesced 64B/lane) -> xT[p][s]*(dtf*xs), tiled f16 ---
    {
        const signed char* xrow = x8 + ((size_t)(b * LSEQ + z * CS + t) * H + h) * PDIM;
        int s8 = t >> 3, sj = t & 7;
        int4 r4 = *(const int4*)xrow;
        int4 r5 = *(const int4*)(xrow + 16);
        int4 r6 = *(const int4*)(xrow + 32);
        int4 r7 = *(const int4*)(xrow + 48);
        int words[16] = {r4.x, r4.y, r4.z, r4.w, r5.x, r5.y, r5.z, r5.w,
                         r6.x, r6.y, r6.z, r6.w, r7.x, r7.y, r7.z, r7.w};
#pragma unroll
        for (int wi = 0; wi < 16; ++wi) {
            int wv = words[wi];
#pragma unroll
            for (int bi = 0; bi < 4; ++bi) {
                int p = wi * 4 + bi;
                int val = (wv << (24 - 8 * bi)) >> 24;
                xT[((p >> 4) * 32 + s8) * XT_PITCH + (p & 15) * 8 + sj] =
                    (_Float16)((float)val * cav);
            }
        }
    }
    __syncthreads();

    int w = t >> 6, lane = t & 63, m = lane & 15, q = lane >> 4;
    floatx4 acc[4][4] = {};   // [j][pt], l16 = 4*j + w

    // ---- inter phase: acc = C_raw @ (prev/16) ----
    const _Float16* shb = statesHT + (size_t)bzh * 8192 + m * 8;
    const _Float16* cbase = C16T + (size_t)bz * 16 * 16 * 128 + m * 8;
    bool interact[4];
#pragma unroll
    for (int j = 0; j < 4; ++j) interact[j] = (cumL[(4 * j + w) * 16] > -80.f);
    for (int kk = 0; kk < 4; ++kk) {
        int n8 = kk * 4 + q;
        half8 bf[4];
#pragma unroll
        for (int pt = 0; pt < 4; ++pt)
            bf[pt] = *(const half8*)(shb + (pt * 16 + n8) * 128);
#pragma unroll
        for (int j = 0; j < 4; ++j) {
            if (!interact[j]) continue;
            half8 ha = *(const half8*)(cbase + ((size_t)(4 * j + w) * 16 + n8) * 128);
#pragma unroll
            for (int pt = 0; pt < 4; ++pt)
                acc[j][pt] = __builtin_amdgcn_mfma_f32_16x16x32_f16(ha, bf[pt], acc[j][pt], 0, 0, 0);
        }
    }
    float Cs16 = (*Cs_p) * 16.0f;
#pragma unroll
    for (int j = 0; j < 4; ++j)
#pragma unroll
        for (int r = 0; r < 4; ++r) {
            float e = __expf(cumL[(4 * j + w) * 16 + q * 4 + r]) * Cs16;
#pragma unroll
            for (int pt = 0; pt < 4; ++pt) acc[j][pt][r] *= e;
        }

    // ---- intra phase (compile-time j bounds; predicate with continue) ----
    const _Float16* cbtb = CBh + (size_t)bz * 16 * 32 * 128 + m * 8;
    for (int kk = 0; kk < 8; ++kk) {
        int jmin = (2 * kk - w + 3) >> 2;
        if (jmin < 0) jmin = 0;
        if (jmin > 3) continue;
        int s8 = kk * 4 + q;
        half8 bf[4];
#pragma unroll
        for (int pt = 0; pt < 4; ++pt)
            bf[pt] = *(const half8*)(xT + (size_t)(pt * 32 + s8) * XT_PITCH + m * 8);
#pragma unroll
        for (int j = 0; j < 4; ++j) {
            if (j < jmin) continue;
            int l16 = 4 * j + w;
            if (cumL[l16 * 16] - cumL[kk * 32 + 31] < -30.f) continue;
            int lA = l16 * 16 + m;
            float cum_l = cumL[lA];
            half8 cb8 = *(const half8*)(cbtb + ((size_t)l16 * 32 + s8) * 128);
            half8 a;
#pragma unroll
            for (int jj = 0; jj < 8; ++jj) {
                int s = kk * 32 + q * 8 + jj;
                float wv = (float)cb8[jj] * __expf(cum_l - cumL[s]);
                a[jj] = (_Float16)((s <= lA) ? wv : 0.f);
            }
#pragma unroll
            for (int pt = 0; pt < 4; ++pt)
                acc[j][pt] = __builtin_amdgcn_mfma_f32_16x16x32_f16(a, bf[pt], acc[j][pt], 0, 0, 0);
        }
    }

    // ---- epilogue: LDS transpose (aliases xT) -> coalesced float4 out, + D*x ----
    float xsDf = (*xs_p) * ((float)qD[h] * (*Ds_p));
    __syncthreads();   // xT dead from here; smem becomes ep
#pragma unroll
    for (int pass = 0; pass < 2; ++pass) {
#pragma unroll
        for (int jj = 0; jj < 2; ++jj) {
            int j = pass * 2 + jj;
            int lbase = (((4 * j + w) * 16) & 127) + q * 4;
#pragma unroll
            for (int r = 0; r < 4; ++r)
#pragma unroll
                for (int pt = 0; pt < 4; ++pt)
                    ep[lbase + r][pt * 16 + m] = acc[j][pt][r];
        }
        __syncthreads();
        int lloc = t >> 1;
        int l = pass * 128 + lloc;
        size_t go = ((size_t)(b * LSEQ + z * CS + l) * H + h) * PDIM + (t & 1) * 32;
        const float* er = &ep[lloc][(t & 1) * 32];
        const signed char* xp8 = x8 + go;
#pragma unroll
        for (int it = 0; it < 8; ++it) {
            int xw = *(const int*)(xp8 + it * 4);
            floatx4 vv;
            vv[0] = er[it * 4 + 0] + (float)((xw << 24) >> 24) * xsDf;
            vv[1] = er[it * 4 + 1] + (float)((xw << 16) >> 24) * xsDf;
            vv[2] = er[it * 4 + 2] + (float)((xw << 8) >> 24) * xsDf;
            vv[3] = er[it * 4 + 3] + (float)(xw >> 24) * xsDf;
            *(floatx4*)(out + go + it * 4) = vv;
        }
        __syncthreads();
    }
}

extern "C" void kernel_launch(void* const* d_in, const int* in_sizes, int n_in,
                              void* d_out, int out_size, void* d_ws, size_t ws_size,
                              hipStream_t stream)
{
    const int* xq = (const int*)d_in[0];
    const int* dt = (const int*)d_in[1];
    const int* Bm = (const int*)d_in[2];
    const int* Cm = (const int*)d_in[3];
    const int* qA = (const int*)d_in[4];
    const int* qD = (const int*)d_in[5];
    const float* dt_bias = (const float*)d_in[6];
    const float* A_scale = (const float*)d_in[7];
    const float* D_scale = (const float*)d_in[8];
    const float* dt_scale = (const float*)d_in[9];
    const float* x_scale = (const float*)d_in[10];
    const float* B_scale = (const float*)d_in[11];
    const float* C_scale = (const float*)d_in[12];
    float* out = (float*)d_out;

    char* ws = (char*)d_ws;
    float* cum           = (float*)(ws);
    float* cAg           = (float*)(ws + 524288);
    float* cdecay        = (float*)(ws + 1048576);
    _Float16* CBh        = (_Float16*)(ws + 1050624);
    _Float16* statesF16  = (_Float16*)(ws + 3147776);
    _Float16* statesHT   = (_Float16*)(ws + 11536384);
    _Float16* Bt16T      = (_Float16*)(ws + 19924992);
    _Float16* C16T       = (_Float16*)(ws + 20973568);
    signed char* x8      = (signed char*)(ws + 22022144);

    kA<<<dim3(416), dim3(256), 0, stream>>>(Bm, Cm, B_scale, C_scale, CBh, Bt16T, C16T);
    k013<<<dim3(512), dim3(256), 0, stream>>>(dt, qA, dt_bias, A_scale, dt_scale,
                                              xq, x_scale, B_scale, Bt16T,
                                              cum, cAg, cdecay, x8, statesF16);
    k4_scan<<<dim3(512), dim3(256), 0, stream>>>(cdecay, statesF16, statesHT);
    k56<<<dim3(512), dim3(256), 0, stream>>>(x8, qD, cum, cAg, CBh, C16T, statesHT,
                                             C_scale, x_scale, D_scale, out);
}